// Round 1
// baseline (813.318 us; speedup 1.0000x reference)
//
#include <hip/hip_runtime.h>

// Problem constants (from reference): L=8, B=2, H=8, S_FULL=4096, S_NEW=4, D=128
// Output: stack((present_k, present_v)) -> (2, L, B, H, S, D) fp32
// Pure memory-bound copy with a tiny dynamic-slice overwrite per (b).

constexpr int Lc = 8, Bc = 2, Hc = 8, Sc = 4096, SNc = 4, Dc = 128;
constexpr int D4 = Dc / 4;                       // 32 float4 per row
constexpr unsigned TOTAL4 = 2u * Lc * Bc * Hc * Sc * D4;  // 2^25 float4 elements

__global__ __launch_bounds__(256) void kv_update_kernel(
    const float4* __restrict__ past_k,
    const float4* __restrict__ past_v,
    const float4* __restrict__ new_k,
    const float4* __restrict__ new_v,
    const int*    __restrict__ tp,
    float4*       __restrict__ out)
{
    unsigned idx = blockIdx.x * 256u + threadIdx.x;  // < 2^25, fits in u32

    // Bit layout (LSB->MSB): d4:5 | s:12 | h:3 | b:1 | l:3 | kv:1
    unsigned d4 = idx & 31u;
    unsigned s  = (idx >> 5) & 4095u;
    unsigned h  = (idx >> 17) & 7u;
    unsigned b  = (idx >> 20) & 1u;
    unsigned l  = (idx >> 21) & 7u;
    unsigned kv = (idx >> 24) & 1u;

    int off = tp[b];   // block-uniform -> scalar load, L2-cached

    float4 val;
    if ((int)s >= off && (int)s < off + SNc) {
        // new_{k,v} layout: (L, B, H, SN, D) -> flat float4 index
        const float4* __restrict__ src = kv ? new_v : new_k;
        unsigned nidx = (((l * Bc + b) * Hc + h) * SNc + (s - (unsigned)off)) * D4 + d4;
        val = src[nidx];
    } else {
        // past index is idx with the kv bit stripped
        const float4* __restrict__ src = kv ? past_v : past_k;
        unsigned pidx = idx & ((1u << 24) - 1u);
        val = src[pidx];
    }
    out[idx] = val;
}

extern "C" void kernel_launch(void* const* d_in, const int* in_sizes, int n_in,
                              void* d_out, int out_size, void* d_ws, size_t ws_size,
                              hipStream_t stream) {
    const float4* past_k = (const float4*)d_in[0];
    const float4* past_v = (const float4*)d_in[1];
    const float4* new_k  = (const float4*)d_in[2];
    const float4* new_v  = (const float4*)d_in[3];
    const int*    tp     = (const int*)d_in[4];
    float4*       out    = (float4*)d_out;

    kv_update_kernel<<<TOTAL4 / 256u, 256, 0, stream>>>(
        past_k, past_v, new_k, new_v, tp, out);
}